// Round 7
// baseline (211.553 us; speedup 1.0000x reference)
//
#include <hip/hip_runtime.h>
#include <hip/hip_bf16.h>

using bf16 = __hip_bfloat16;
typedef __attribute__((ext_vector_type(8))) short short8;
typedef __attribute__((ext_vector_type(4))) short s4v;
typedef __attribute__((ext_vector_type(4))) float float4v;
typedef __attribute__((ext_vector_type(4))) float f32x4;
typedef __attribute__((ext_vector_type(16))) float f32x16;
typedef __attribute__((ext_vector_type(4))) int i32x4;

#define MFMA16(a, b, c) __builtin_amdgcn_mfma_f32_16x16x32_bf16((a), (b), (c), 0, 0, 0)
#define MFMA32(a, b, c) __builtin_amdgcn_mfma_f32_32x32x16_bf16((a), (b), (c), 0, 0, 0)

// async global->LDS, 16B per lane, dest = wave-uniform base + lane*16
#define GLD_LDS16(g, l)                                            \
    __builtin_amdgcn_global_load_lds(                              \
        (const __attribute__((address_space(1))) void*)(g),        \
        (__attribute__((address_space(3))) void*)(l), 16, 0, 0)

constexpr int Bc = 2;
constexpr int Sc = 2048;
constexpr int Hc = 16;
constexpr int DKc = 64;
constexpr int Dc = 1024;
constexpr size_t MEG = 1024 * 1024;

union BFU { bf16 h; short s; };
union PKU { i32x4 i; short8 s; };

__device__ inline short bfbits(float f) {
    BFU u; u.h = __float2bfloat16(f); return u.s;
}

__device__ inline float bits2f(short s) {
    BFU u; u.s = s; return __bfloat162float(u.h);
}

// packed f32x2 -> bf16x2 (low = a, high = b); RNE, single VOP3
__device__ inline unsigned cvtpk(float a, float b) {
    unsigned r;
    asm("v_cvt_pk_bf16_f32 %0, %1, %2" : "=v"(r) : "v"(a), "v"(b));
    return r;
}

__device__ inline short8 load_cvt8(const float* __restrict__ p) {
    f32x4 a = *(const f32x4*)p;
    f32x4 b = *(const f32x4*)(p + 4);
    short8 r;
    r[0] = bfbits(a[0]); r[1] = bfbits(a[1]); r[2] = bfbits(a[2]); r[3] = bfbits(a[3]);
    r[4] = bfbits(b[0]); r[5] = bfbits(b[1]); r[6] = bfbits(b[2]); r[7] = bfbits(b[3]);
    return r;
}

// ---------------------------------------------------------------------------
// One-shot fp32 -> bf16 conversion of x, Wq, Wk, Wv, Wo (8M elems) into ws.
// ---------------------------------------------------------------------------
__global__ __launch_bounds__(256) void cvt_kernel(
    const float* __restrict__ x, const float* __restrict__ Wq,
    const float* __restrict__ Wk, const float* __restrict__ Wv,
    const float* __restrict__ Wo, bf16* __restrict__ dst)
{
    const size_t i = ((size_t)blockIdx.x * 256 + threadIdx.x) * 8;
    const float* s;
    if      (i < 4 * MEG) s = x  + i;
    else if (i < 5 * MEG) s = Wq + (i - 4 * MEG);
    else if (i < 6 * MEG) s = Wk + (i - 5 * MEG);
    else if (i < 7 * MEG) s = Wv + (i - 6 * MEG);
    else                  s = Wo + (i - 7 * MEG);
    *(short8*)(dst + i) = load_cvt8(s);
}

// ---------------------------------------------------------------------------
// Fused QKV projection, m97-style BK=32. grid (24, 32): sel = bx>>3.
// Q pre-scaled by (1/8)*log2e, row-major (b,h,s,d).
// K and V are written in MFMA-FRAGMENT-MAJOR order for the 32x32x16 attn:
//   K frag elem: [bh][s>>6][ (kv=(s>>5)&1)*4 + (d>>4) ][ (s&31)+32*((d>>3)&1) ][ d&7 ]
//   V frag elem: [bh][s>>6][ (dv=d>>5)*4 + ((s>>4)&3) ][ (d&31)+32*((s>>3)&1) ][ s&7 ]
// so attn staging is contiguous 1KB chunks and ds_read_b128 = base+lane*16
// (conflict-free, no swizzle math).
// ---------------------------------------------------------------------------
__global__ __launch_bounds__(256) void qkv_gemm_kernel(
    const bf16* __restrict__ x,
    const bf16* __restrict__ Wq, const float* __restrict__ bq,
    const bf16* __restrict__ Wk, const float* __restrict__ bk,
    const bf16* __restrict__ Wv, const float* __restrict__ bv,
    bf16* __restrict__ q_ws, bf16* __restrict__ k_ws, bf16* __restrict__ v_ws)
{
    constexpr int BM = 128, BN = 128, BK = 32;
    __shared__ __align__(16) bf16 sA[BM * BK];
    __shared__ __align__(16) bf16 sB[BN * BK];

    const int bx = blockIdx.x;
    const int sel = bx >> 3;               // 0=Q 1=K 2=V
    const int n0 = (bx & 7) * BN;
    const int m0 = blockIdx.y * BM;

    const bf16* __restrict__ Wsel = (sel == 0) ? Wq : ((sel == 1) ? Wk : Wv);
    const float* __restrict__ bsel = (sel == 0) ? bq : ((sel == 1) ? bk : bv);

    const int t = threadIdx.x;
    const int lane = t & 63;
    const int wave = t >> 6;
    const int ln = lane & 15;
    const int qd = lane >> 4;
    const int wm = (wave >> 1) * 64;
    const int wn = (wave & 1) * 64;

    const int gr = lane >> 2;              // 0..15: row within 16-row chunk
    const int gc = (lane & 3) * 8;         // 0,8,16,24

    float4v acc[4][4];
#pragma unroll
    for (int i = 0; i < 4; i++)
#pragma unroll
        for (int j = 0; j < 4; j++) acc[i][j] = (float4v)0.0f;

    for (int kk = 0; kk < Dc; kk += BK) {
        __syncthreads();
#pragma unroll
        for (int cc = 0; cc < 2; cc++) {
            const int c = wave * 2 + cc;
            GLD_LDS16(x    + (size_t)(m0 + c * 16 + gr) * Dc + kk + gc, &sA[c * 512]);
            GLD_LDS16(Wsel + (size_t)(n0 + c * 16 + gr) * Dc + kk + gc, &sB[c * 512]);
        }
        __syncthreads();

        short8 af[4], wf[4];
#pragma unroll
        for (int i = 0; i < 4; i++)
            af[i] = *(const short8*)&sA[(wm + i * 16 + ln) * BK + qd * 8];
#pragma unroll
        for (int j = 0; j < 4; j++)
            wf[j] = *(const short8*)&sB[(wn + j * 16 + ln) * BK + qd * 8];
#pragma unroll
        for (int i = 0; i < 4; i++)
#pragma unroll
            for (int j = 0; j < 4; j++)
                acc[i][j] = MFMA16(af[i], wf[j], acc[i][j]);
    }

    constexpr float QSCALE = 0.125f * 1.44269504088896f;

#pragma unroll
    for (int j = 0; j < 4; j++) {
        const int n = n0 + wn + j * 16 + ln;
        const float bias = bsel[n];
        const int h_ = n >> 6, d_ = n & 63;
#pragma unroll
        for (int i = 0; i < 4; i++) {
            const int mbase = m0 + wm + i * 16 + qd * 4;
            const int b_ = mbase >> 11, s0_ = mbase & 2047;
            if (sel == 2) {                // V frag-order: 4 s-contig -> 8B store
                const int dv_ = d_ >> 5, cV = d_ & 31;
                const int ktg = s0_ >> 6, ksl = (s0_ >> 4) & 3;
                const int hiV = (s0_ >> 3) & 1, i0 = s0_ & 7;
                s4v pk;
#pragma unroll
                for (int r = 0; r < 4; r++)
                    pk[r] = bfbits(acc[i][j][r] + bias);
                *(s4v*)&v_ws[(size_t)(b_ * Hc + h_) * Sc * DKc + ktg * 4096
                             + (dv_ * 4 + ksl) * 512 + (cV + 32 * hiV) * 8 + i0] = pk;
            } else if (sel == 1) {         // K frag-order: scalar stores
                const int ks_ = d_ >> 4, hiK = (d_ >> 3) & 1, ii = d_ & 7;
#pragma unroll
                for (int r = 0; r < 4; r++) {
                    const int s_ = s0_ + r;
                    const int ktg = s_ >> 6, kv = (s_ >> 5) & 1, cK = s_ & 31;
                    k_ws[(size_t)(b_ * Hc + h_) * Sc * DKc + ktg * 4096
                         + (kv * 4 + ks_) * 512 + (cK + 32 * hiK) * 8 + ii] =
                        __float2bfloat16(acc[i][j][r] + bias);
                }
            } else {                       // Q row-major, pre-scaled
#pragma unroll
                for (int r = 0; r < 4; r++) {
                    const int s_ = s0_ + r;
                    q_ws[(((size_t)(b_ * Hc + h_)) * Sc + s_) * DKc + d_] =
                        __float2bfloat16((acc[i][j][r] + bias) * QSCALE);
                }
            }
        }
    }
}

// ---------------------------------------------------------------------------
// Flash attention v9: 32x32 MFMA + in-register softmax (no sP LDS round trip)
// + frag-major K/V staging (contiguous GLD chunks, conflict-free ds_read at
// base+lane*16, zero swizzle math). 4 waves x 32 qrows = 128 qrows/block;
// split-S z=2 (16 ktiles of 64 keys); grid (32,16,2)=1024 -> 4 blocks/CU
// (LDS 32KB), 16 waves/CU.
//   Swapped QK^T (A=K,B=Q), 32x32x16: D col = qrow = lane&31, row = key =
//   (reg&3)+8*(reg>>2)+4*(lane>>5)  [m74/m101-verified layout]. So lane c
//   holds P[qrow=c][keys 8q+4hi+t] -> exp2 in regs, cvt_pk to bf16 pairs,
//   shfl_xor(32) exchanges the 4-key half-rows, 4 cndmask/kslice build the
//   PV A-frag in-lane (qrow stays lane-resident; no LDS, no barrier dep).
//   Denominator: ones-column B-frag MFMA (col 0 lanes); broadcast via shfl.
// ---------------------------------------------------------------------------
__global__ __launch_bounds__(256, 4) void attn_kernel(
    const bf16* __restrict__ q_ws, const bf16* __restrict__ kf_ws,
    const bf16* __restrict__ vf_ws, bf16* __restrict__ po0,
    bf16* __restrict__ po1, float* __restrict__ l_ws)
{
    constexpr int NKT = 16;                // 16 ktiles x 64 keys = 1024/split
    __shared__ __align__(16) bf16 sK[2][8 * 512];   // [buf][kv*4+ks][lane*8]
    __shared__ __align__(16) bf16 sV[2][8 * 512];   // [buf][dv*4+ksl][lane*8]

    const int bh = blockIdx.x;
    const int qt = blockIdx.y;
    const int sp = blockIdx.z;
    const int t = threadIdx.x;
    const int lane = t & 63;
    const int wave = t >> 6;               // 0..3
    const int c = lane & 31;
    const int hi = lane >> 5;

    const bf16* __restrict__ Qbase = q_ws + (size_t)bh * Sc * DKc
                                   + (size_t)(qt * 128 + wave * 32) * DKc;
    const bf16* __restrict__ KF = kf_ws + ((size_t)bh * Sc + sp * 1024) * DKc;
    const bf16* __restrict__ VF = vf_ws + ((size_t)bh * Sc + sp * 1024) * DKc;

    // Q B-frags, loop-invariant (16 VGPRs): B[n=qrow=c][k=ks*16+hi*8+i]
    short8 qf[4];
#pragma unroll
    for (int ks = 0; ks < 4; ks++)
        qf[ks] = *(const short8*)(Qbase + (size_t)c * DKc + ks * 16 + hi * 8);

    // ones B-frag: B[n][k] = 1 iff n==0 (denominator column)
    short8 ones8;
    {
        const short ob = (c == 0) ? (short)0x3F80 : (short)0;
#pragma unroll
        for (int i = 0; i < 8; i++) ones8[i] = ob;
    }

    auto stage = [&](int buf, int kt2) {
#pragma unroll
        for (int cc = 0; cc < 4; cc++) {
            const int cid = (wave << 2) + cc;      // 0..15, wave-uniform
            if (cid < 8)
                GLD_LDS16(KF + (size_t)kt2 * 4096 + cid * 512 + lane * 8,
                          &sK[buf][cid * 512]);
            else
                GLD_LDS16(VF + (size_t)kt2 * 4096 + (cid - 8) * 512 + lane * 8,
                          &sV[buf][(cid - 8) * 512]);
        }
    };

    f32x16 oacc0 = (f32x16)0.0f;           // O[:, d = 0..31]
    f32x16 oacc1 = (f32x16)0.0f;           // O[:, d = 32..63]
    f32x16 den   = (f32x16)0.0f;           // col 0 = row sums

    stage(0, 0);

    for (int kt = 0; kt < NKT; kt++) {
        const int cur = kt & 1;
        __syncthreads();                   // drains vmcnt: buf[cur] ready
        if (kt + 1 < NKT) stage(cur ^ 1, kt + 1);

#pragma unroll
        for (int kv = 0; kv < 2; kv++) {
            // S^T tile: A=K[key], B=Q[qrow]; lane holds qrow=c, keys 8q+4hi+t
            f32x16 sacc = (f32x16)0.0f;
            __builtin_amdgcn_s_setprio(1);
#pragma unroll
            for (int ks = 0; ks < 4; ks++) {
                const short8 kfr = *(const short8*)
                    &sK[cur][(kv * 4 + ks) * 512 + lane * 8];
                sacc = MFMA32(kfr, qf[ks], sacc);
            }
            __builtin_amdgcn_s_setprio(0);

            // P = exp2(S^T): 16 f32 -> 8 packed bf16 dwords; swap half-rows
            unsigned s0[4][2], sw[4][2];
#pragma unroll
            for (int q = 0; q < 4; q++)
#pragma unroll
                for (int j = 0; j < 2; j++)
                    s0[q][j] = cvtpk(exp2f(sacc[q * 4 + j * 2]),
                                     exp2f(sacc[q * 4 + j * 2 + 1]));
#pragma unroll
            for (int q = 0; q < 4; q++)
#pragma unroll
                for (int j = 0; j < 2; j++)
                    sw[q][j] = (unsigned)__shfl_xor((int)s0[q][j], 32, 64);

            // PV: A[m=qrow][k=key] built in-lane; B=V^T frag from LDS
            __builtin_amdgcn_s_setprio(1);
#pragma unroll
            for (int m = 0; m < 2; m++) {  // kslice = kv*2+m (16 keys each)
                PKU u;
                u.i[0] = (int)(hi ? sw[2 * m + 1][0] : s0[2 * m][0]);
                u.i[1] = (int)(hi ? sw[2 * m + 1][1] : s0[2 * m][1]);
                u.i[2] = (int)(hi ? s0[2 * m + 1][0] : sw[2 * m][0]);
                u.i[3] = (int)(hi ? s0[2 * m + 1][1] : sw[2 * m][1]);
                const short8 ap = u.s;
                const int ksl = kv * 2 + m;
                const short8 vf0 = *(const short8*)
                    &sV[cur][(0 + ksl) * 512 + lane * 8];
                const short8 vf1 = *(const short8*)
                    &sV[cur][(4 + ksl) * 512 + lane * 8];
                oacc0 = MFMA32(ap, vf0, oacc0);
                oacc1 = MFMA32(ap, vf1, oacc1);
                den   = MFMA32(ap, ones8, den);
            }
            __builtin_amdgcn_s_setprio(0);
        }
    }

    // Epilogue: den col 0 lives in lanes c==0 (both hi halves).
    const int b_ = bh >> 4, h_ = bh & 15;
    bf16* __restrict__ po = sp ? po1 : po0;
    if (c == 0) {
#pragma unroll
        for (int r = 0; r < 16; r++) {
            const int qrow = (r & 3) + 8 * (r >> 2) + 4 * hi;
            l_ws[(size_t)(sp * 32 + bh) * Sc + qt * 128 + wave * 32 + qrow] =
                den[r];
        }
    }
#pragma unroll
    for (int r = 0; r < 16; r++) {
        const float l = __shfl(den[r], lane & 32, 64);  // lane (0, hi)
        const float inv = 1.0f / l;
        const int qrow = (r & 3) + 8 * (r >> 2) + 4 * hi;
        const int s_ = qt * 128 + wave * 32 + qrow;
        const size_t rowb = (((size_t)(b_ * Sc + s_)) * Hc + h_) * DKc;
        po[rowb + c]      = __float2bfloat16(oacc0[r] * inv);
        po[rowb + 32 + c] = __float2bfloat16(oacc1[r] * inv);
    }
}

// ---------------------------------------------------------------------------
// Combine the two split-S partials: O = (l0*O0 + l1*O1)/(l0+l1), elementwise
// over (b,s,h,d); writes final bf16 into po0 (= ao_ws) in place.
// ---------------------------------------------------------------------------
__global__ __launch_bounds__(256) void combine_kernel(
    bf16* po0, const bf16* __restrict__ po1, const float* __restrict__ l_ws)
{
    const size_t gid = (size_t)blockIdx.x * 256 + threadIdx.x;
    const size_t e = gid * 8;              // 8 d-elems within one (b,s,h) row
    const int flat = (int)(e >> 6);        // (b*Sc + s)*Hc + h
    const int h_ = flat & 15;
    const int bs = flat >> 4;
    const int b_ = bs >> 11, s_ = bs & 2047;
    const int bh = b_ * Hc + h_;
    const float l0 = l_ws[(size_t)bh * Sc + s_];
    const float l1 = l_ws[(size_t)(32 + bh) * Sc + s_];
    const float inv = 1.0f / (l0 + l1);
    const float w0 = l0 * inv, w1 = l1 * inv;
    const short8 a = *(const short8*)(po0 + e);
    const short8 b = *(const short8*)(po1 + e);
    short8 o;
#pragma unroll
    for (int i = 0; i < 8; i++)
        o[i] = bfbits(bits2f(a[i]) * w0 + bits2f(b[i]) * w1);
    *(short8*)(po0 + e) = o;
}

// ---------------------------------------------------------------------------
// Output projection, m97-style BK=32. grid (8, 32), block 256.
// ---------------------------------------------------------------------------
__global__ __launch_bounds__(256) void out_gemm_kernel(
    const bf16* __restrict__ A, const bf16* __restrict__ Wo,
    const float* __restrict__ bo, float* __restrict__ out)
{
    constexpr int BM = 128, BN = 128, BK = 32;
    __shared__ __align__(16) bf16 sA[BM * BK];
    __shared__ __align__(16) bf16 sB[BN * BK];

    const int n0 = blockIdx.x * BN;
    const int m0 = blockIdx.y * BM;

    const int t = threadIdx.x;
    const int lane = t & 63;
    const int wave = t >> 6;
    const int ln = lane & 15;
    const int qd = lane >> 4;
    const int wm = (wave >> 1) * 64;
    const int wn = (wave & 1) * 64;

    const int gr = lane >> 2;
    const int gc = (lane & 3) * 8;

    float4v acc[4][4];
#pragma unroll
    for (int i = 0; i < 4; i++)
#pragma unroll
        for (int j = 0; j < 4; j++) acc[i][j] = (float4v)0.0f;

    for (int kk = 0; kk < Dc; kk += BK) {
        __syncthreads();
#pragma unroll
        for (int cc = 0; cc < 2; cc++) {
            const int c = wave * 2 + cc;
            GLD_LDS16(A  + (size_t)(m0 + c * 16 + gr) * Dc + kk + gc, &sA[c * 512]);
            GLD_LDS16(Wo + (size_t)(n0 + c * 16 + gr) * Dc + kk + gc, &sB[c * 512]);
        }
        __syncthreads();

        short8 af[4], wf[4];
#pragma unroll
        for (int i = 0; i < 4; i++)
            af[i] = *(const short8*)&sA[(wm + i * 16 + ln) * BK + qd * 8];
#pragma unroll
        for (int j = 0; j < 4; j++)
            wf[j] = *(const short8*)&sB[(wn + j * 16 + ln) * BK + qd * 8];
#pragma unroll
        for (int i = 0; i < 4; i++)
#pragma unroll
            for (int j = 0; j < 4; j++)
                acc[i][j] = MFMA16(af[i], wf[j], acc[i][j]);
    }

#pragma unroll
    for (int j = 0; j < 4; j++) {
        const int n = n0 + wn + j * 16 + ln;
        const float bias = bo[n];
#pragma unroll
        for (int i = 0; i < 4; i++) {
            const int mbase = m0 + wm + i * 16 + qd * 4;
#pragma unroll
            for (int r = 0; r < 4; r++) {
                const int m = mbase + r;
                out[(size_t)m * Dc + n] = acc[i][j][r] + bias;
            }
        }
    }
}

// ---------------------------------------------------------------------------
extern "C" void kernel_launch(void* const* d_in, const int* in_sizes, int n_in,
                              void* d_out, int out_size, void* d_ws, size_t ws_size,
                              hipStream_t stream)
{
    const float* x  = (const float*)d_in[0];
    const float* Wq = (const float*)d_in[1];
    const float* bq = (const float*)d_in[2];
    const float* Wk = (const float*)d_in[3];
    const float* bk = (const float*)d_in[4];
    const float* Wv = (const float*)d_in[5];
    const float* bv = (const float*)d_in[6];
    const float* Wo = (const float*)d_in[7];
    const float* bo = (const float*)d_in[8];
    float* out = (float*)d_out;

    bf16* base  = (bf16*)d_ws;
    bf16* q_ws  = base;                      // (b,h,s,d), pre-scaled
    bf16* k_ws  = base + 4 * MEG;            // K frag-major (see qkv_gemm)
    bf16* v_ws  = base + 8 * MEG;            // V frag-major (see qkv_gemm)
    bf16* ao_ws = base + 12 * MEG;           // (b,s,h,d): split-0 partial, then final
    bf16* xb    = base + 16 * MEG;           // bf16 inputs; reused as split-1 partial
    bf16* po1   = xb;                        // (b,s,h,d) partial O of split 1 (8 MB)
    bf16* wqb   = base + 20 * MEG;           // reused as l_ws after qkv_gemm
    float* l_ws = (float*)wqb;               // [split][bh][s] denominators (512 KB)
    bf16* wkb   = base + 21 * MEG;
    bf16* wvb   = base + 22 * MEG;
    bf16* wob   = base + 23 * MEG;

    cvt_kernel<<<dim3(4096), 256, 0, stream>>>(x, Wq, Wk, Wv, Wo, xb);
    qkv_gemm_kernel<<<dim3(24, 32), 256, 0, stream>>>(
        xb, wqb, bq, wkb, bk, wvb, bv, q_ws, k_ws, v_ws);
    attn_kernel<<<dim3(32, 16, 2), 256, 0, stream>>>(
        q_ws, k_ws, v_ws, ao_ws, po1, l_ws);
    combine_kernel<<<dim3(2048), 256, 0, stream>>>(ao_ws, po1, l_ws);
    out_gemm_kernel<<<dim3(8, 32), 256, 0, stream>>>(ao_ws, wob, bo, out);
}